// Round 1
// baseline (84.437 us; speedup 1.0000x reference)
//
#include <hip/hip_runtime.h>
#include <stdint.h>

#define B_   2048
#define C_   1000
#define N2   4096
#define D_   256
#define JSPLIT 8

typedef float  f32x4  __attribute__((ext_vector_type(4)));
typedef short  short8 __attribute__((ext_vector_type(8)));

__device__ __forceinline__ float waveSum(float v){
#pragma unroll
  for (int o = 32; o; o >>= 1) v += __shfl_xor(v, o, 64);
  return v;
}
__device__ __forceinline__ float waveMax(float v){
#pragma unroll
  for (int o = 32; o; o >>= 1) v = fmaxf(v, __shfl_xor(v, o, 64));
  return v;
}

// ---------------- Kernel 1: per-row softmax stats, tp, counts, new_target ----
__global__ __launch_bounds__(256) void k1_softmax_tp(
    const float* __restrict__ outputs, const float* __restrict__ Y,
    float* __restrict__ nt, int* __restrict__ tp, int* __restrict__ counts)
{
  const int i = blockIdx.x;                 // 0..B_-1
  const float* o = outputs + (size_t)i * C_;
  const float* y = Y + (size_t)i * C_;
  const int t = threadIdx.x;
  __shared__ float sm[4], ss[4], sv[4];
  __shared__ int   si[4];

  float m = -3.4e38f;
  for (int c = t; c < C_; c += 256) m = fmaxf(m, o[c]);
  m = waveMax(m);
  if ((t & 63) == 0) sm[t >> 6] = m;
  __syncthreads();
  m = fmaxf(fmaxf(sm[0], sm[1]), fmaxf(sm[2], sm[3]));

  float s = 0.f; float bv = -3.4e38f; int bi = 0x7fffffff;
  for (int c = t; c < C_; c += 256){
    float oc = o[c];
    if (y[c] > 0.f){
      s += __expf(oc - m);
      if (oc > bv || (oc == bv && c < bi)){ bv = oc; bi = c; }
    }
  }
  s = waveSum(s);
#pragma unroll
  for (int off = 32; off; off >>= 1){
    float ov = __shfl_xor(bv, off, 64);
    int   oi = __shfl_xor(bi, off, 64);
    if (ov > bv || (ov == bv && oi < bi)){ bv = ov; bi = oi; }
  }
  if ((t & 63) == 0){ ss[t >> 6] = s; sv[t >> 6] = bv; si[t >> 6] = bi; }
  __syncthreads();
  s = ss[0] + ss[1] + ss[2] + ss[3];
  bv = sv[0]; bi = si[0];
#pragma unroll
  for (int w = 1; w < 4; ++w)
    if (sv[w] > bv || (sv[w] == bv && si[w] < bi)){ bv = sv[w]; bi = si[w]; }

  const float inv = 1.f / s;
  for (int c = t; c < C_; c += 256)
    nt[(size_t)i * C_ + c] = (y[c] > 0.f) ? __expf(o[c] - m) * inv : 0.f;

  if (t == 0){
    if (bi < 0 || bi >= C_) bi = 0;
    tp[i] = bi;
    atomicAdd(counts + bi, 1);
  }
}

// ---------------- Kernel 2: cf (concat of feature halves) -> bf16 ------------
__global__ __launch_bounds__(256) void k2_cvt(
    const float* __restrict__ feat, unsigned short* __restrict__ cfb)
{
  int idx = blockIdx.x * 256 + threadIdx.x;  // 0 .. 4096*256-1 (grid exact)
  int r = idx >> 8, d = idx & 255;
  int src = (r < B_) ? (r * 512 + d) : ((r - B_) * 512 + 256 + d);
  uint32_t u = __float_as_uint(feat[src]);
  u += 0x7fffu + ((u >> 16) & 1u);           // RNE to bf16
  cfb[idx] = (unsigned short)(u >> 16);
}

// ---------------- Kernel 3: maskB (B x B) + row sums --------------------------
__global__ __launch_bounds__(256) void k3_mask(
    const float* __restrict__ Y, const float* __restrict__ ps,
    const int* __restrict__ tp, const int* __restrict__ counts,
    float* __restrict__ maskB, float* __restrict__ rowsum)
{
  const int i = blockIdx.x;                  // 0..B_-1
  const float* y = Y + (size_t)i * C_;
  const float* p = ps + (size_t)i * C_;
  float loc = 0.f;
  for (int j = threadIdx.x; j < B_; j += 256){
    int tj = tp[j];
    float v = y[tj] * p[tj] / (float)counts[tj];
    maskB[(size_t)i * B_ + j] = v;
    loc += v;
  }
  loc = waveSum(loc);
  __shared__ float sr[4];
  if ((threadIdx.x & 63) == 0) sr[threadIdx.x >> 6] = loc;
  __syncthreads();
  if (threadIdx.x == 0) rowsum[i] = sr[0] + sr[1] + sr[2] + sr[3];
}

// ---------------- Kernel 4: fused bf16 MFMA GEMM + row reductions -------------
// grid (N2/64, JSPLIT), 256 threads (4 waves). Each wave owns 16 "i" columns
// (MFMA n-axis), iterates the block's j-range (MFMA m-axis) in 64-row LDS chunks.
__global__ __launch_bounds__(256) void k4_gemm(
    const unsigned short* __restrict__ cfb, const float* __restrict__ maskB,
    float* __restrict__ gE, float* __restrict__ gS1)
{
  __shared__ uint4 lds4[2048];               // 64 rows x 512 B = 32 KiB
  const int tid = threadIdx.x;
  const int w = tid >> 6;
  const int l = tid & 63;
  const int Ib = blockIdx.x * 64;
  const int Jb = blockIdx.y * (N2 / JSPLIT);
  const int irow = Ib + w * 16 + (l & 15);
  const int ip = irow & (B_ - 1);

  // B-operand fragments: rows i of cf, k-chunk (l>>4)*8, held for whole kernel
  short8 bfrag[8];
#pragma unroll
  for (int kk = 0; kk < 8; ++kk)
    bfrag[kk] = *reinterpret_cast<const short8*>(
        cfb + ((size_t)irow << 8) + (kk << 5) + ((l >> 4) << 3));

  float E = 0.f, S1 = 0.f;

  for (int ch = 0; ch < (N2 / JSPLIT) / 64; ++ch){
    const int Jc = Jb + ch * 64;
    __syncthreads();
    // stage 64 j-rows, XOR-swizzled (byte ^= (row&7)<<4), linear LDS dest
#pragma unroll
    for (int rep = 0; rep < 8; ++rep){
      int q    = tid + (rep << 8);
      int rowl = q >> 5;
      int c16  = (q & 31) ^ (rowl & 7);      // pre-swizzled source slot
      lds4[q] = *reinterpret_cast<const uint4*>(
          cfb + ((size_t)(Jc + rowl) << 8) + (c16 << 3));
    }
    __syncthreads();

#pragma unroll
    for (int s = 0; s < 4; ++s){
      f32x4 acc = {0.f, 0.f, 0.f, 0.f};
      const int arow = s * 16 + (l & 15);
#pragma unroll
      for (int kk = 0; kk < 8; ++kk){
        int idx16 = arow * 32 + ((kk * 4 + (l >> 4)) ^ (l & 7));
        short8 af = *reinterpret_cast<const short8*>(&lds4[idx16]);
        acc = __builtin_amdgcn_mfma_f32_16x16x32_bf16(af, bfrag[kk], acc, 0, 0, 0);
      }
      // epilogue: lane holds D[m][n], m=j=(l>>4)*4+r (4 consecutive), n=i=l&15
      const int jg0 = Jc + s * 16 + ((l >> 4) << 2);
      const int jp  = jg0 & (B_ - 1);
      const float4 mq = *reinterpret_cast<const float4*>(maskB + (size_t)ip * B_ + jp);
      const float mv[4] = {mq.x, mq.y, mq.z, mq.w};
#pragma unroll
      for (int r = 0; r < 4; ++r){
        float d = acc[r] * 10.f;             // adc = dot / T
        if (jg0 + r != irow){                // skip exact diagonal
          E  += __expf(d - 10.f);            // M = 10 (row max = diagonal)
          S1 += mv[r] * d;
        }
      }
    }
  }
  // combine lanes sharing the same i (l, l+16, l+32, l+48)
  E  += __shfl_xor(E, 16, 64);  E  += __shfl_xor(E, 32, 64);
  S1 += __shfl_xor(S1, 16, 64); S1 += __shfl_xor(S1, 32, 64);
  if ((l >> 4) == 0){
    atomicAdd(&gE[irow],  E);
    atomicAdd(&gS1[irow], S1);
  }
}

// ---------------- Kernel 5: final loss reduction -------------------------------
__global__ __launch_bounds__(256) void k5_final(
    const float* __restrict__ gE, const float* __restrict__ gS1,
    const float* __restrict__ rowsum, const float* __restrict__ maskB,
    float* __restrict__ out)
{
  float loc = 0.f;
  for (int i = threadIdx.x; i < N2; i += 256){
    int ipp = i & (B_ - 1);
    float msum = 2.f * rowsum[ipp] - maskB[(size_t)ipp * B_ + ipp];
    // contrib = S1 - msum*M - msum*log(E) with M=10
    loc += gS1[i] - msum * (10.f + logf(gE[i]));
  }
  loc = waveSum(loc);
  __shared__ float sr[4];
  if ((threadIdx.x & 63) == 0) sr[threadIdx.x >> 6] = loc;
  __syncthreads();
  if (threadIdx.x == 0){
    float tot = sr[0] + sr[1] + sr[2] + sr[3];
    out[0] = -(0.1f / 0.07f) * (tot / (float)N2);
  }
}

// ---------------- launch -------------------------------------------------------
extern "C" void kernel_launch(void* const* d_in, const int* in_sizes, int n_in,
                              void* d_out, int out_size, void* d_ws, size_t ws_size,
                              hipStream_t stream)
{
  const float* outputs  = (const float*)d_in[0];   // (2B, C) f32
  const float* features = (const float*)d_in[1];   // (B, 2, D) f32 (normalized)
  const float* Y        = (const float*)d_in[2];   // (B, C) f32
  const float* ps       = (const float*)d_in[3];   // (B, C) f32
  float* out = (float*)d_out;                      // [loss, new_target(B*C)]

  char* ws = (char*)d_ws;
  int*   counts = (int*)(ws);                      // 1000 ints   @ 0
  int*   tp     = (int*)(ws + 4096);               // 2048 ints   @ 4096
  float* rowsum = (float*)(ws + 12288);            // 2048 f32    @ 12288
  float* gE     = (float*)(ws + 20480);            // 4096 f32    @ 20480
  float* gS1    = (float*)(ws + 36864);            // 4096 f32    @ 36864
  unsigned short* cfb = (unsigned short*)(ws + 53248);   // 4096*256 bf16 (2 MiB)
  float* maskB  = (float*)(ws + 2150400);          // 2048*2048 f32 (16 MiB)

  hipMemsetAsync(ws, 0, 53248, stream);            // zero counts/tp/rowsum/gE/gS1

  k1_softmax_tp<<<B_, 256, 0, stream>>>(outputs, Y, out + 1, tp, counts);
  k2_cvt<<<(N2 * D_) / 256, 256, 0, stream>>>(features, cfb);
  k3_mask<<<B_, 256, 0, stream>>>(Y, ps, tp, counts, maskB, rowsum);
  k4_gemm<<<dim3(N2 / 64, JSPLIT), 256, 0, stream>>>(cfb, maskB, gE, gS1);
  k5_final<<<1, 256, 0, stream>>>(gE, gS1, rowsum, maskB, out);
}